// Round 14
// baseline (5550.938 us; speedup 1.0000x reference)
//
#include <hip/hip_runtime.h>
#include <math.h>

#define NTHR 512
#define BT 4

__device__ __forceinline__ float fast_tanh(float x) {
    float ax = fabsf(x);
    float e  = __expf(-2.0f * ax);                       // in (0,1], never overflows
    float r  = (1.0f - e) * __builtin_amdgcn_rcpf(1.0f + e);
    return copysignf(r, x);
}

// quad_perm DPP add (VALU pipe): 0xB1 = xor1, 0x4E = xor2 within quads.
template <int CTRL>
__device__ __forceinline__ float dpp_add(float x) {
    int yi = __builtin_amdgcn_update_dpp(0, __builtin_bit_cast(int, x), CTRL, 0xF, 0xF, true);
    return x + __builtin_bit_cast(float, yi);
}

// Two-group software pipeline: groups g0={b0,b0+1}, g1={b0+2,b0+3} run the same
// 5-phase chain offset by 2 phases. Each barrier-delimited slot executes
// phase(g0,p) + phase(g1,p-2): two independent streams fill each other's
// dependency-stall bubbles. Weights are shared across groups (same k/j map).
__global__ __launch_bounds__(NTHR, 2)
void odernn_kernel(const float* __restrict__ quat,   // [1024][64][4]
                   const float* __restrict__ W1,     // [68][256]
                   const float* __restrict__ b1,     // [256]
                   const float* __restrict__ W2,     // [256][256]
                   const float* __restrict__ b2,     // [256]
                   const float* __restrict__ W3,     // [256][64]
                   const float* __restrict__ b3,     // [64]
                   float* __restrict__ out)          // [1024*64] hfinal, then [1024][64][8][64] traj
{
    __shared__ __align__(16) float sH1[2][2 * 264];
    __shared__ __align__(16) float sH2[2][2 * 264];
    __shared__ __align__(16) float sC1[2][2 * 264];
    __shared__ __align__(16) float sY [2][2 * 72];
    __shared__ __align__(16) float sRB[2][8 * 2 * 264];   // B partials per group
    __shared__ __align__(16) float sRD[2][8 * 2 * 64];    // D partials per group

    const int t = threadIdx.x;
    const int w = t >> 6;            // wave 0..7
    const int l = t & 63;            // lane
    const int b0 = blockIdx.x * BT;

    // ---- A: thread (j-pair j0, k-quarter ksa, 2 batches); lane output (bA, jA) ----
    const int ksa = l & 3;
    const int j0  = (w * 16 + (l >> 2)) * 2;
    const int bA  = l & 1;
    const int jA  = j0 + ((l >> 1) & 1);
    // ---- B: wave = k-slice of 32, lane = j-quad ----
    const int kb2 = w * 32;
    // ---- C: 1 output/thread ----
    const int jC = t & 255;
    const int bC = t >> 8;
    // ---- D: k-slice = (w, l&3) (quad-DPP folds quads), j-quad = l>>2 ----
    const int kb3 = ((w << 2) | (l & 3)) * 8;
    const int j03 = (l >> 2) * 4;
    // ---- E owners: t<128, batch-in-group rbE = w (0/1), dim rjE ----
    const int rbE = w;
    const int rjE = l;

    // ---- weights -> registers (dup-free, SHARED by both groups) ----
    float w1r[32];                                   // W1h[ksa*16+k][j0+jj]
    #pragma unroll
    for (int k = 0; k < 16; ++k) {
        float2 v = *(const float2*)&W1[(ksa * 16 + k) * 256 + j0];
        w1r[k * 2 + 0] = v.x; w1r[k * 2 + 1] = v.y;
    }
    float w2r[128];                                  // W2[kb2+k][l*4+jj]
    const float4* __restrict__ W2v4 = (const float4*)W2;
    #pragma unroll
    for (int k = 0; k < 32; ++k) {
        float4 v = W2v4[(size_t)(kb2 + k) * 64 + l];
        w2r[k * 4 + 0] = v.x; w2r[k * 4 + 1] = v.y;
        w2r[k * 4 + 2] = v.z; w2r[k * 4 + 3] = v.w;
    }
    float w3r[32];                                   // W3[kb3+k][j03+jj]
    #pragma unroll
    for (int k = 0; k < 8; ++k) {
        float4 v = *(const float4*)&W3[(kb3 + k) * 64 + j03];
        w3r[k * 4 + 0] = v.x; w3r[k * 4 + 1] = v.y;
        w3r[k * 4 + 2] = v.z; w3r[k * 4 + 3] = v.w;
    }
    float w1q[4];                                    // q-part of W1, col jC
    #pragma unroll
    for (int m = 0; m < 4; ++m) w1q[m] = W1[(64 + m) * 256 + jC];

    const float rb1  = b1[jC];
    const float rb2c = b2[jC];
    const float b3r  = b3[l];

    float rH0 = (rjE == 0) ? 1.0f : 0.0f;  // meaningful for t<128
    float rH1 = rH0;
    float k10 = 0.f, k20 = 0.f, k30 = 0.f;
    float k11 = 0.f, k21 = 0.f, k31 = 0.f;
    if (t < 128) {
        sY[0][rbE * 72 + rjE] = rH0;
        sY[1][rbE * 72 + rjE] = rH1;
    }

    const float dt = 1.0f / 7.0f;
    float* __restrict__ traj = out + 1024 * 64;

    // ---------- phase bodies ----------
    auto Hp = [&](int g, int s_, float rHv) {
        float4 qv = *(const float4*)&quat[((size_t)(b0 + 2 * g + bC) * 64 + s_) * 4];
        sC1[g][bC * 264 + jC] =
            fmaf(qv.x, w1q[0], fmaf(qv.y, w1q[1], fmaf(qv.z, w1q[2], fmaf(qv.w, w1q[3], rb1))));
        if (t < 128)
            traj[(((size_t)(b0 + 2 * g + rbE) * 64 + s_) * 8 + 0) * 64 + rjE] = rHv;
    };

    auto Ap = [&](int g) {
        float a[2][2];
        a[0][0] = 0.f; a[0][1] = 0.f; a[1][0] = 0.f; a[1][1] = 0.f;
        const float4* y4 = (const float4*)&sY[g][0];
        #pragma unroll
        for (int kk = 0; kk < 4; ++kk) {
            float4 yv0 = y4[0 * 18 + ksa * 4 + kk];
            float4 yv1 = y4[1 * 18 + ksa * 4 + kk];
            #pragma unroll
            for (int r = 0; r < 4; ++r) {
                float w0  = w1r[(kk * 4 + r) * 2 + 0];
                float w1v = w1r[(kk * 4 + r) * 2 + 1];
                float f0 = ((const float*)&yv0)[r];
                float f1 = ((const float*)&yv1)[r];
                a[0][0] = fmaf(f0, w0, a[0][0]); a[0][1] = fmaf(f0, w1v, a[0][1]);
                a[1][0] = fmaf(f1, w0, a[1][0]); a[1][1] = fmaf(f1, w1v, a[1][1]);
            }
        }
        #pragma unroll
        for (int bb = 0; bb < 2; ++bb)
            #pragma unroll
            for (int jj = 0; jj < 2; ++jj) {
                a[bb][jj] = dpp_add<0xB1>(a[bb][jj]);
                a[bb][jj] = dpp_add<0x4E>(a[bb][jj]);
            }
        float z0 = (l & 1) ? a[1][0] : a[0][0];
        float z1 = (l & 1) ? a[1][1] : a[0][1];
        float o  = (l & 2) ? z1 : z0;
        float c  = sC1[g][bA * 264 + jA];
        sH1[g][bA * 264 + jA] = fast_tanh(o + c);
    };

    auto Bp = [&](int g) {
        float acc[2][4];
        #pragma unroll
        for (int bb = 0; bb < 2; ++bb)
            #pragma unroll
            for (int jj = 0; jj < 4; ++jj) acc[bb][jj] = 0.0f;
        #pragma unroll
        for (int k4 = 0; k4 < 8; ++k4) {
            const int k = kb2 + k4 * 4;
            float4 h0  = *(const float4*)&sH1[g][0 * 264 + k];
            float4 h1v = *(const float4*)&sH1[g][1 * 264 + k];
            #pragma unroll
            for (int r = 0; r < 4; ++r) {
                const int wi = (k4 * 4 + r) * 4;
                float f0 = ((const float*)&h0)[r];
                float f1 = ((const float*)&h1v)[r];
                #pragma unroll
                for (int jj = 0; jj < 4; ++jj) {
                    acc[0][jj] = fmaf(f0, w2r[wi + jj], acc[0][jj]);
                    acc[1][jj] = fmaf(f1, w2r[wi + jj], acc[1][jj]);
                }
            }
        }
        *(float4*)&sRB[g][w * 528 + 0 * 264 + l * 4] =
            make_float4(acc[0][0], acc[0][1], acc[0][2], acc[0][3]);
        *(float4*)&sRB[g][w * 528 + 1 * 264 + l * 4] =
            make_float4(acc[1][0], acc[1][1], acc[1][2], acc[1][3]);
    };

    auto Cp = [&](int g) {
        float v0 = rb2c, v1 = 0.0f;
        #pragma unroll
        for (int ks = 0; ks < 8; ks += 2) {
            v0 += sRB[g][ks * 528 + bC * 264 + jC];
            v1 += sRB[g][(ks + 1) * 528 + bC * 264 + jC];
        }
        sH2[g][bC * 264 + jC] = fast_tanh(v0 + v1);
    };

    auto Dp = [&](int g) {
        float acc[2][4];
        #pragma unroll
        for (int bb = 0; bb < 2; ++bb)
            #pragma unroll
            for (int jj = 0; jj < 4; ++jj) acc[bb][jj] = 0.0f;
        #pragma unroll
        for (int kk = 0; kk < 2; ++kk) {
            const int k = kb3 + kk * 4;
            float4 h0  = *(const float4*)&sH2[g][0 * 264 + k];
            float4 h1v = *(const float4*)&sH2[g][1 * 264 + k];
            #pragma unroll
            for (int r = 0; r < 4; ++r) {
                const int wi = (kk * 4 + r) * 4;
                float f0 = ((const float*)&h0)[r];
                float f1 = ((const float*)&h1v)[r];
                #pragma unroll
                for (int jj = 0; jj < 4; ++jj) {
                    acc[0][jj] = fmaf(f0, w3r[wi + jj], acc[0][jj]);
                    acc[1][jj] = fmaf(f1, w3r[wi + jj], acc[1][jj]);
                }
            }
        }
        #pragma unroll
        for (int bb = 0; bb < 2; ++bb)
            #pragma unroll
            for (int jj = 0; jj < 4; ++jj) {
                acc[bb][jj] = dpp_add<0xB1>(acc[bb][jj]);
                acc[bb][jj] = dpp_add<0x4E>(acc[bb][jj]);
            }
        // lane q = l&3 picks (batch q&1, j-half q>>1); write float2
        float z0 = (l & 1) ? acc[1][0] : acc[0][0];
        float z1 = (l & 1) ? acc[1][2] : acc[0][2];
        float o0 = (l & 2) ? z1 : z0;
        z0 = (l & 1) ? acc[1][1] : acc[0][1];
        z1 = (l & 1) ? acc[1][3] : acc[0][3];
        float o1 = (l & 2) ? z1 : z0;
        *(float2*)&sRD[g][w * 128 + (l & 1) * 64 + j03 + ((l >> 1) & 1) * 2] =
            make_float2(o0, o1);
    };

    auto Ep = [&](int g, float& eH, float& e1, float& e2, float& e3,
                  int s_, int step_, int mode_) {
        if (t < 128) {
            const int base = rbE * 64 + rjE;
            float s0 = b3r, s1 = 0.f, s2 = 0.f, s3 = 0.f;
            #pragma unroll
            for (int wk = 0; wk < 8; wk += 4) {
                s0 += sRD[g][(wk + 0) * 128 + base];
                s1 += sRD[g][(wk + 1) * 128 + base];
                s2 += sRD[g][(wk + 2) * 128 + base];
                s3 += sRD[g][(wk + 3) * 128 + base];
            }
            float kk = (s0 + s1) + (s2 + s3);
            float ynew;
            if (mode_ == 1) {
                e1 = kk;
                ynew = fmaf(dt * (1.0f / 3.0f), e1, eH);
            } else if (mode_ == 2) {
                e2 = kk;
                ynew = fmaf(dt, e2 - e1 * (1.0f / 3.0f), eH);
            } else if (mode_ == 3) {
                e3 = kk;
                ynew = fmaf(dt, e1 - e2 + e3, eH);
            } else {
                eH = fmaf(dt * 0.125f, e1 + 3.0f * (e2 + e3) + kk, eH);
                ynew = eH;
                traj[(((size_t)(b0 + 2 * g + rbE) * 64 + s_) * 8 + step_) * 64 + rjE] = eH;
            }
            sY[g][rbE * 72 + rjE] = ynew;
        }
    };

    // ---------- pipelined schedule ----------
    for (int s = 0; s < 64; ++s) {
        // T1: header g0 || D(g1, it=27 of prev token)
        Hp(0, s, rH0);
        if (s > 0) Dp(1);
        __syncthreads();
        // T2: A(g0,0) || E(g1, prev token final)
        Ap(0);
        if (s > 0) Ep(1, rH1, k11, k21, k31, s - 1, 7, 4);
        __syncthreads();
        // T3: B(g0,0) || header g1
        Bp(0);
        Hp(1, s, rH1);
        __syncthreads();
        // T4: C(g0,0) || A(g1,0)
        Cp(0); Ap(1);
        __syncthreads();
        Dp(0); Bp(1);
        __syncthreads();
        Ep(0, rH0, k10, k20, k30, s, 1, 1); Cp(1);
        __syncthreads();
        // steady frames: g0 at iteration it, g1 finishing it-1 then doing it
        #pragma unroll 1
        for (int it = 1; it < 28; ++it) {
            const int mode  = (it & 3) + 1;
            const int step  = (it >> 2) + 1;
            const int modeP = ((it - 1) & 3) + 1;
            const int stepP = ((it - 1) >> 2) + 1;
            Ap(0); Dp(1);
            __syncthreads();
            Bp(0); Ep(1, rH1, k11, k21, k31, s, stepP, modeP);
            __syncthreads();
            Cp(0); Ap(1);
            __syncthreads();
            Dp(0); Bp(1);
            __syncthreads();
            Ep(0, rH0, k10, k20, k30, s, step, mode); Cp(1);
            __syncthreads();
        }
    }
    // drain g1's final iteration of token 63
    Dp(1);
    __syncthreads();
    Ep(1, rH1, k11, k21, k31, 63, 7, 4);

    if (t < 128) {
        out[(size_t)(b0 + rbE) * 64 + rjE]     = rH0;
        out[(size_t)(b0 + 2 + rbE) * 64 + rjE] = rH1;
    }
}

extern "C" void kernel_launch(void* const* d_in, const int* in_sizes, int n_in,
                              void* d_out, int out_size, void* d_ws, size_t ws_size,
                              hipStream_t stream) {
    const float* quat = (const float*)d_in[0];
    const float* W1   = (const float*)d_in[1];
    const float* b1   = (const float*)d_in[2];
    const float* W2   = (const float*)d_in[3];
    const float* b2   = (const float*)d_in[4];
    const float* W3   = (const float*)d_in[5];
    const float* b3   = (const float*)d_in[6];
    float* out = (float*)d_out;

    odernn_kernel<<<1024 / BT, NTHR, 0, stream>>>(quat, W1, b1, W2, b2, W3, b3, out);
}

// Round 15
// 5472.263 us; speedup vs baseline: 1.0144x; 1.0144x over previous
//
#include <hip/hip_runtime.h>
#include <math.h>

#define NTHR 512
#define BT 4

__device__ __forceinline__ float fast_tanh(float x) {
    float ax = fabsf(x);
    float e  = __expf(-2.0f * ax);                       // in (0,1], never overflows
    float r  = (1.0f - e) * __builtin_amdgcn_rcpf(1.0f + e);
    return copysignf(r, x);
}

// quad_perm DPP add (VALU pipe): 0xB1 = xor1, 0x4E = xor2 within quads.
template <int CTRL>
__device__ __forceinline__ float dpp_add(float x) {
    int yi = __builtin_amdgcn_update_dpp(0, __builtin_bit_cast(int, x), CTRL, 0xF, 0xF, true);
    return x + __builtin_bit_cast(float, yi);
}

__global__ __launch_bounds__(NTHR, 2)
void odernn_kernel(const float* __restrict__ quat,   // [1024][64][4]
                   const float* __restrict__ W1,     // [68][256]
                   const float* __restrict__ b1,     // [256]
                   const float* __restrict__ W2,     // [256][256]
                   const float* __restrict__ b2,     // [256]
                   const float* __restrict__ W3,     // [256][64]
                   const float* __restrict__ b3,     // [64]
                   float* __restrict__ out)          // [1024*64] hfinal, then [1024][64][8][64] traj
{
    // Padded strides: activation rows 264 floats; sY rows 72.
    __shared__ __align__(16) float sRed[8448];      // 33.8 KB
    __shared__ __align__(16) float sH1[4 * 264];
    __shared__ __align__(16) float sH2[4 * 264];
    __shared__ __align__(16) float sC1[4 * 264];
    __shared__ __align__(16) float sY [4 * 72];

    const int t = threadIdx.x;
    const int w = t >> 6;            // wave 0..7
    const int l = t & 63;            // lane
    const int q = l & 3;             // quad lane id (batch owner after DPP reduce)
    const int b0 = blockIdx.x * BT;

    // ---- A (L1): thread owns (j-pair j0..j0+1, 4 batches, k-quarter) ----
    const int ksa = l & 3;                    // k-quarter 0..3 (16 k each)
    const int j0  = (w * 16 + (l >> 2)) * 2;  // j-pair base, 0..254
    // ---- B (L2): wave = k-slice of 32, lane = j-quad ----
    const int kb2 = w * 32;
    // ---- C: thread owns (j-pair jpc, batch bcc) -> b64 LDS ops ----
    const int jpc = (t & 127) * 2;   // 0..254
    const int bcc = t >> 7;          // 0..3
    // ---- D (L3): k-slice 0..31 = (wave, lane&3); j-quad = l>>2 ----
    const int ksd = (w << 2) | q;
    const int kb3 = ksd * 8;
    const int u3  = l >> 2;          // j-quad 0..15
    const int j03 = u3 * 4;
    // ---- E (RK4, t<256): batch rb = wave, state dim rj = lane ----
    const int rb = (t >> 6) & 3;
    const int rj = l;

    // ---- weights -> registers (dup-free) ----
    float w1r[32];                                   // W1h[ksa*16+k][j0+jj]
    #pragma unroll
    for (int k = 0; k < 16; ++k) {
        float2 v = *(const float2*)&W1[(ksa * 16 + k) * 256 + j0];
        w1r[k * 2 + 0] = v.x; w1r[k * 2 + 1] = v.y;
    }
    float w2r[128];                                  // W2[kb2+k][l*4+jj]
    const float4* __restrict__ W2v4 = (const float4*)W2;
    #pragma unroll
    for (int k = 0; k < 32; ++k) {
        float4 v = W2v4[(size_t)(kb2 + k) * 64 + l];
        w2r[k * 4 + 0] = v.x; w2r[k * 4 + 1] = v.y;
        w2r[k * 4 + 2] = v.z; w2r[k * 4 + 3] = v.w;
    }
    float w3r[32];                                   // W3[kb3+k][j03+jj]
    #pragma unroll
    for (int k = 0; k < 8; ++k) {
        float4 v = *(const float4*)&W3[(kb3 + k) * 64 + j03];
        w3r[k * 4 + 0] = v.x; w3r[k * 4 + 1] = v.y;
        w3r[k * 4 + 2] = v.z; w3r[k * 4 + 3] = v.w;
    }
    const int j1c = t & 255;                         // sC1 producer col (t<256)
    float w1q[4];                                    // q-part of W1
    #pragma unroll
    for (int m = 0; m < 4; ++m) w1q[m] = W1[(64 + m) * 256 + j1c];

    const float rb1   = b1[j1c];
    const float2 rb2v = *(const float2*)&b2[jpc];
    const float rb3e  = b3[rj];

    float rH  = (rj == 0) ? 1.0f : 0.0f;   // meaningful for t<256
    float rk1 = 0.0f, rk2 = 0.0f, rk3 = 0.0f;
    if (t < 256) sY[rb * 72 + rj] = rH;

    const float dt = 1.0f / 7.0f;
    float* __restrict__ traj = out + 1024 * 64;

    for (int s = 0; s < 64; ++s) {
        // ---- per-token: c1 = b1 + quat @ W1q ; record initial state ----
        if (t < 256) {
            float4 q0 = *(const float4*)&quat[((size_t)(b0 + 0) * 64 + s) * 4];
            float4 q1 = *(const float4*)&quat[((size_t)(b0 + 1) * 64 + s) * 4];
            float4 q2 = *(const float4*)&quat[((size_t)(b0 + 2) * 64 + s) * 4];
            float4 q3 = *(const float4*)&quat[((size_t)(b0 + 3) * 64 + s) * 4];
            sC1[0 * 264 + t] = fmaf(q0.x, w1q[0], fmaf(q0.y, w1q[1], fmaf(q0.z, w1q[2], fmaf(q0.w, w1q[3], rb1))));
            sC1[1 * 264 + t] = fmaf(q1.x, w1q[0], fmaf(q1.y, w1q[1], fmaf(q1.z, w1q[2], fmaf(q1.w, w1q[3], rb1))));
            sC1[2 * 264 + t] = fmaf(q2.x, w1q[0], fmaf(q2.y, w1q[1], fmaf(q2.z, w1q[2], fmaf(q2.w, w1q[3], rb1))));
            sC1[3 * 264 + t] = fmaf(q3.x, w1q[0], fmaf(q3.y, w1q[1], fmaf(q3.z, w1q[2], fmaf(q3.w, w1q[3], rb1))));
            traj[(((size_t)(b0 + rb) * 64 + s) * 8 + 0) * 64 + rj] = rH;
        }
        __syncthreads();

        for (int step = 1; step < 8; ++step) {
            #pragma unroll
            for (int mode = 1; mode <= 4; ++mode) {
                // ---------- A: h1 = tanh(y @ W1h + c1); k-split 4 via quad-DPP ----------
                {
                    float a[4][2];
                    #pragma unroll
                    for (int bb = 0; bb < 4; ++bb) { a[bb][0] = 0.0f; a[bb][1] = 0.0f; }
                    const float4* y4 = (const float4*)&sY[0];
                    #pragma unroll
                    for (int kk = 0; kk < 4; ++kk) {
                        float4 yv0 = y4[0 * 18 + ksa * 4 + kk];
                        float4 yv1 = y4[1 * 18 + ksa * 4 + kk];
                        float4 yv2 = y4[2 * 18 + ksa * 4 + kk];
                        float4 yv3 = y4[3 * 18 + ksa * 4 + kk];
                        #pragma unroll
                        for (int r = 0; r < 4; ++r) {
                            float w0 = w1r[(kk * 4 + r) * 2 + 0];
                            float w1v = w1r[(kk * 4 + r) * 2 + 1];
                            float f0 = ((const float*)&yv0)[r];
                            float f1 = ((const float*)&yv1)[r];
                            float f2 = ((const float*)&yv2)[r];
                            float f3 = ((const float*)&yv3)[r];
                            a[0][0] = fmaf(f0, w0, a[0][0]); a[0][1] = fmaf(f0, w1v, a[0][1]);
                            a[1][0] = fmaf(f1, w0, a[1][0]); a[1][1] = fmaf(f1, w1v, a[1][1]);
                            a[2][0] = fmaf(f2, w0, a[2][0]); a[2][1] = fmaf(f2, w1v, a[2][1]);
                            a[3][0] = fmaf(f3, w0, a[3][0]); a[3][1] = fmaf(f3, w1v, a[3][1]);
                        }
                    }
                    #pragma unroll
                    for (int bb = 0; bb < 4; ++bb) {
                        #pragma unroll
                        for (int jj = 0; jj < 2; ++jj) {
                            a[bb][jj] = dpp_add<0xB1>(a[bb][jj]);
                            a[bb][jj] = dpp_add<0x4E>(a[bb][jj]);
                        }
                    }
                    float z0 = (l & 1) ? a[1][0] : a[0][0];
                    float z1 = (l & 1) ? a[3][0] : a[2][0];
                    float o0 = (l & 2) ? z1 : z0;
                    z0 = (l & 1) ? a[1][1] : a[0][1];
                    z1 = (l & 1) ? a[3][1] : a[2][1];
                    float o1 = (l & 2) ? z1 : z0;
                    float2 c = *(const float2*)&sC1[q * 264 + j0];
                    float2 h = make_float2(fast_tanh(o0 + c.x), fast_tanh(o1 + c.y));
                    *(float2*)&sH1[q * 264 + j0] = h;
                }
                __syncthreads();
                // ---------- B: layer-2 partials (W2 in registers) ----------
                {
                    float acc[4][4];
                    #pragma unroll
                    for (int bb = 0; bb < 4; ++bb)
                        #pragma unroll
                        for (int jj = 0; jj < 4; ++jj) acc[bb][jj] = 0.0f;
                    #pragma unroll
                    for (int k4 = 0; k4 < 8; ++k4) {
                        const int k = kb2 + k4 * 4;
                        float4 h0 = *(const float4*)&sH1[0 * 264 + k];
                        float4 h1v = *(const float4*)&sH1[1 * 264 + k];
                        float4 h2v = *(const float4*)&sH1[2 * 264 + k];
                        float4 h3v = *(const float4*)&sH1[3 * 264 + k];
                        #pragma unroll
                        for (int r = 0; r < 4; ++r) {
                            const int wi = (k4 * 4 + r) * 4;
                            float f0 = ((const float*)&h0)[r];
                            float f1 = ((const float*)&h1v)[r];
                            float f2 = ((const float*)&h2v)[r];
                            float f3 = ((const float*)&h3v)[r];
                            #pragma unroll
                            for (int jj = 0; jj < 4; ++jj) {
                                acc[0][jj] = fmaf(f0, w2r[wi + jj], acc[0][jj]);
                                acc[1][jj] = fmaf(f1, w2r[wi + jj], acc[1][jj]);
                                acc[2][jj] = fmaf(f2, w2r[wi + jj], acc[2][jj]);
                                acc[3][jj] = fmaf(f3, w2r[wi + jj], acc[3][jj]);
                            }
                        }
                    }
                    // partials: sRed as [8 ks][4 b][264 j]
                    #pragma unroll
                    for (int bb = 0; bb < 4; ++bb)
                        *(float4*)&sRed[w * 1056 + bb * 264 + l * 4] =
                            make_float4(acc[bb][0], acc[bb][1], acc[bb][2], acc[bb][3]);
                }
                __syncthreads();
                // ---------- C: layer-2 reduce + tanh (j-pair per thread, b64 LDS ops) ----------
                {
                    float v0x = rb2v.x, v0y = rb2v.y, v1x = 0.0f, v1y = 0.0f;
                    #pragma unroll
                    for (int ks = 0; ks < 8; ks += 2) {
                        float2 pa = *(const float2*)&sRed[ks * 1056 + bcc * 264 + jpc];
                        float2 pb = *(const float2*)&sRed[(ks + 1) * 1056 + bcc * 264 + jpc];
                        v0x += pa.x; v0y += pa.y;
                        v1x += pb.x; v1y += pb.y;
                    }
                    *(float2*)&sH2[bcc * 264 + jpc] =
                        make_float2(fast_tanh(v0x + v1x), fast_tanh(v0y + v1y));
                }
                __syncthreads();
                // ---------- D: layer-3 partials; quad-DPP folds k-split 32 -> 8 ----------
                {
                    float acc[4][4];
                    #pragma unroll
                    for (int bb = 0; bb < 4; ++bb)
                        #pragma unroll
                        for (int jj = 0; jj < 4; ++jj) acc[bb][jj] = 0.0f;
                    #pragma unroll
                    for (int kk = 0; kk < 2; ++kk) {
                        const int k = kb3 + kk * 4;
                        float4 h0 = *(const float4*)&sH2[0 * 264 + k];
                        float4 h1v = *(const float4*)&sH2[1 * 264 + k];
                        float4 h2v = *(const float4*)&sH2[2 * 264 + k];
                        float4 h3v = *(const float4*)&sH2[3 * 264 + k];
                        #pragma unroll
                        for (int r = 0; r < 4; ++r) {
                            const int wi = (kk * 4 + r) * 4;
                            float f0 = ((const float*)&h0)[r];
                            float f1 = ((const float*)&h1v)[r];
                            float f2 = ((const float*)&h2v)[r];
                            float f3 = ((const float*)&h3v)[r];
                            #pragma unroll
                            for (int jj = 0; jj < 4; ++jj) {
                                acc[0][jj] = fmaf(f0, w3r[wi + jj], acc[0][jj]);
                                acc[1][jj] = fmaf(f1, w3r[wi + jj], acc[1][jj]);
                                acc[2][jj] = fmaf(f2, w3r[wi + jj], acc[2][jj]);
                                acc[3][jj] = fmaf(f3, w3r[wi + jj], acc[3][jj]);
                            }
                        }
                    }
                    #pragma unroll
                    for (int bb = 0; bb < 4; ++bb)
                        #pragma unroll
                        for (int jj = 0; jj < 4; ++jj) {
                            acc[bb][jj] = dpp_add<0xB1>(acc[bb][jj]);
                            acc[bb][jj] = dpp_add<0x4E>(acc[bb][jj]);
                        }
                    float o0, o1, o2, o3;
                    {
                        float z0 = (l & 1) ? acc[1][0] : acc[0][0];
                        float z1 = (l & 1) ? acc[3][0] : acc[2][0];
                        o0 = (l & 2) ? z1 : z0;
                        z0 = (l & 1) ? acc[1][1] : acc[0][1];
                        z1 = (l & 1) ? acc[3][1] : acc[2][1];
                        o1 = (l & 2) ? z1 : z0;
                        z0 = (l & 1) ? acc[1][2] : acc[0][2];
                        z1 = (l & 1) ? acc[3][2] : acc[2][2];
                        o2 = (l & 2) ? z1 : z0;
                        z0 = (l & 1) ? acc[1][3] : acc[0][3];
                        z1 = (l & 1) ? acc[3][3] : acc[2][3];
                        o3 = (l & 2) ? z1 : z0;
                    }
                    // D partials: sRed as [8 w][4 b][64 j], j-quad slot XOR'd by batch
                    ((float4*)sRed)[w * 64 + q * 16 + (u3 ^ q)] = make_float4(o0, o1, o2, o3);
                }
                __syncthreads();
                // ---------- E: 8-way reduce + RK4 (3/8-rule) ----------
                if (t < 256) {
                    const int jb = rb * 64 + (((rj >> 2) ^ rb) * 4) + (rj & 3);
                    float s0 = rb3e, s1 = 0.0f, s2 = 0.0f, s3 = 0.0f;
                    #pragma unroll
                    for (int wk = 0; wk < 8; wk += 4) {
                        s0 += sRed[(wk + 0) * 256 + jb];
                        s1 += sRed[(wk + 1) * 256 + jb];
                        s2 += sRed[(wk + 2) * 256 + jb];
                        s3 += sRed[(wk + 3) * 256 + jb];
                    }
                    float k = (s0 + s1) + (s2 + s3);
                    float ynew;
                    if (mode == 1) {
                        rk1 = k;
                        ynew = fmaf(dt * (1.0f / 3.0f), rk1, rH);
                    } else if (mode == 2) {
                        rk2 = k;
                        ynew = fmaf(dt, rk2 - rk1 * (1.0f / 3.0f), rH);
                    } else if (mode == 3) {
                        rk3 = k;
                        ynew = fmaf(dt, rk1 - rk2 + rk3, rH);
                    } else {
                        rH = fmaf(dt * 0.125f, rk1 + 3.0f * (rk2 + rk3) + k, rH);
                        ynew = rH;
                        traj[(((size_t)(b0 + rb) * 64 + s) * 8 + step) * 64 + rj] = rH;
                    }
                    sY[rb * 72 + rj] = ynew;
                }
                __syncthreads();
            }
        }
    }
    if (t < 256) out[(size_t)(b0 + rb) * 64 + rj] = rH;
}

extern "C" void kernel_launch(void* const* d_in, const int* in_sizes, int n_in,
                              void* d_out, int out_size, void* d_ws, size_t ws_size,
                              hipStream_t stream) {
    const float* quat = (const float*)d_in[0];
    const float* W1   = (const float*)d_in[1];
    const float* b1   = (const float*)d_in[2];
    const float* W2   = (const float*)d_in[3];
    const float* b2   = (const float*)d_in[4];
    const float* W3   = (const float*)d_in[5];
    const float* b3   = (const float*)d_in[6];
    float* out = (float*)d_out;

    odernn_kernel<<<1024 / BT, NTHR, 0, stream>>>(quat, W1, b1, W2, b2, W3, b3, out);
}